// Round 22
// baseline (91.769 us; speedup 1.0000x reference)
//
#include <hip/hip_runtime.h>

typedef __attribute__((ext_vector_type(4))) float  f32x4;
typedef __attribute__((ext_vector_type(8))) short  bf16x8;
typedef __attribute__((ext_vector_type(4))) int    i32x4;
typedef __attribute__((ext_vector_type(2))) unsigned short u16x2;
typedef __attribute__((ext_vector_type(4))) unsigned short u16x4;
typedef __attribute__((ext_vector_type(2))) unsigned int   u32x2;

// ws layout (bytes)
#define OBUF_OFF  0u            // 65536*128 bf16 = 16 MiB
#define QSEP_OFF  16777216u     // [256 i][4 h][256 j][32 c] bf16 = 16 MiB (q, scale*log2e folded)
#define KSEP_OFF  33554432u     // [256 i][4 h][256 j][32 c] bf16 = 16 MiB
#define GSEP_OFF  50331648u     // [256 i][4 h][256 j][32 c] bf16 = 16 MiB (sigmoid(g), pre-gated)
#define VT_OFF    67108864u     // [256 i][4 h][32 c][256 j] bf16 = 16 MiB
#define BIAS_OFF  83886080u     // [4 h][64 k4][256 q][4] f32 = 1 MiB (pre-scaled by log2e)
#define WCAT_OFF  84934656u     // [516][128] bf16 (q*scale*log2e, k, v, g, w_b*log2e rows 512-515)
#define WO_OFF    85066752u     // [128][128] bf16

#define LOG2E 1.4426950408889634f

__device__ __forceinline__ unsigned short f2bf(float x){
  unsigned int u = __builtin_bit_cast(unsigned int, x);
  unsigned int r = (u + 0x7FFFu + ((u>>16)&1u)) >> 16;
  return (unsigned short)r;
}
__device__ __forceinline__ float bf2f(unsigned short b){
  unsigned int u = ((unsigned int)b) << 16;
  return __builtin_bit_cast(float, u);
}
__device__ __forceinline__ unsigned packbf2(float lo, float hi){
  return __builtin_amdgcn_perm(__builtin_bit_cast(unsigned, hi),
                               __builtin_bit_cast(unsigned, lo), 0x07060302u);
}

// ---------------- kernel 1: weight prep only (tiny: 322 blocks) --------------------
__global__ __launch_bounds__(256) void prep_w_kernel(
    const float* __restrict__ w_qkv, const float* __restrict__ w_g,
    const float* __restrict__ w_b,  const float* __restrict__ w_o,
    unsigned short* __restrict__ Wcat, unsigned short* __restrict__ Wo_bf)
{
  int idx = blockIdx.x*256 + threadIdx.x;
  if (idx < 516*128){
    int r = idx >> 7, d = idx & 127;
    float v;
    if (r < 384)      v = w_qkv[idx];
    else if (r < 512) v = w_g[(r-384)*128 + d];
    else              v = w_b[(r-512)*128 + d] * LOG2E;
    if (r < 128) v *= 0.17677669529663689f * LOG2E;  // C^-0.5 * log2e into q rows
    Wcat[idx] = f2bf(v);
  } else if (idx < 516*128 + 128*128){
    int k = idx - 516*128;
    Wo_bf[k] = f2bf(w_o[k]);
  }
}

// ---------------- kernel 2: LN (fused) + qkv+g GEMM + pair-bias, 64-row tiles ------
// Round-21: gemm latency-bound with serial per-block chain (4 levers nulled).
// This round: HALVE the tile -> 1024 blocks of 64 rows, LDS 16KiB, 4 blocks/CU x
// 8 waves = up to 32 waves/CU. Serial chain per block halves; inter-phase bubbles
// fill with other blocks' work (no barriers needed across blocks). VGPR goes DOWN
// (acc[2][2]); epilogue store pattern identical to round-19 (coalescing verified).
__global__ __launch_bounds__(512) void gemm_qkvg_kernel(
    const float* __restrict__ Z_raw, const float* __restrict__ ln_gamma,
    const float* __restrict__ ln_beta, const unsigned short* __restrict__ Wcat,
    const float* __restrict__ b_g,
    unsigned short* __restrict__ Qsep, unsigned short* __restrict__ Ksep,
    unsigned short* __restrict__ Gsep, unsigned short* __restrict__ Vt,
    float* __restrict__ bias4)
{
  __shared__ __align__(16) char sA[16384];   // [64 rows][256 B] swizzled (LN output)
  int rb = blockIdx.x;
  int t = threadIdx.x;
  int wid = t>>6, lane = t&63;
  // LN of this block's 64 rows -> sA (2 rows/wave/pass, 8 waves => 4 passes)
  {
    int half = lane >> 5, l32 = lane & 31;
    int i0 = rb >> 2, j0 = (rb & 3) * 64;
    f32x4 g4  = *reinterpret_cast<const f32x4*>(&ln_gamma[l32*4]);
    f32x4 be4 = *reinterpret_cast<const f32x4*>(&ln_beta[l32*4]);
    #pragma unroll
    for (int it=0; it<4; ++it){
      int lr = it*16 + wid*2 + half;    // local row 0..63
      int j  = j0 + lr;
      f32x4 v = *reinterpret_cast<const f32x4*>(&Z_raw[((size_t)(j*256 + i0))*128 + l32*4]);
      float s  = (v[0]+v[1]) + (v[2]+v[3]);
      float sq = (v[0]*v[0]+v[1]*v[1]) + (v[2]*v[2]+v[3]*v[3]);
      #pragma unroll
      for (int mk=1; mk<32; mk<<=1){ s += __shfl_xor(s, mk, 64); sq += __shfl_xor(sq, mk, 64); }
      float mu   = s * (1.0f/128.0f);
      float var  = sq*(1.0f/128.0f) - mu*mu;
      float rstd = rsqrtf(var + 1e-5f);
      u16x4 o;
      #pragma unroll
      for (int e=0; e<4; ++e) o[e] = f2bf((v[e]-mu)*rstd*g4[e] + be4[e]);
      int off = lr*256 + l32*8;
      *reinterpret_cast<u16x4*>(sA + (off ^ ((lr&7)<<4))) = o;
    }
  }
  __syncthreads();
  int wr = wid>>2, wc = wid&3;          // 32-row half x 32-col quarter
  int lcol = lane & 15, lk16 = (lane>>4)*16;
  int r0 = (lane>>4)*4, hi = lane>>4;

  #pragma unroll
  for (int cb=0; cb<4; ++cb){
    f32x4 acc[2][2] = {};
    #pragma unroll
    for (int ks=0; ks<4; ++ks){
      bf16x8 a[2], b[2];
      #pragma unroll
      for (int mi=0; mi<2; ++mi){
        int row = wr*32 + mi*16 + lcol;
        int off = row*256 + ks*64 + lk16;
        a[mi] = *reinterpret_cast<const bf16x8*>(sA + (off ^ ((row&7)<<4)));
      }
      #pragma unroll
      for (int ni=0; ni<2; ++ni){
        int brow = cb*128 + wc*32 + ni*16 + lcol;   // weight row (L2-resident)
        b[ni] = *reinterpret_cast<const bf16x8*>(&Wcat[brow*128 + ks*32 + hi*8]);
      }
      #pragma unroll
      for (int mi=0; mi<2; ++mi)
        #pragma unroll
        for (int ni=0; ni<2; ++ni)
          acc[mi][ni] = __builtin_amdgcn_mfma_f32_16x16x32_bf16(a[mi], b[ni], acc[mi][ni], 0,0,0);
    }
    if (cb != 2){
      unsigned short* __restrict__ dst = (cb==0) ? Qsep : (cb==1 ? Ksep : Gsep);
      #pragma unroll
      for (int mi=0; mi<2; ++mi)
        #pragma unroll
        for (int ni=0; ni<2; ++ni){
          int e = wc*32 + ni*16 + lcol;      // h = e>>5, c = e&31
          int hh = e>>5, c = e&31;
          int mrow = rb*64 + wr*32 + mi*16 + r0;
          #pragma unroll
          for (int r=0; r<4; ++r){
            int m = mrow + r;
            int i2 = m >> 8, j2 = m & 255;
            float val = acc[mi][ni][r];
            if (cb == 3){
              float gl = val + b_g[e];
              val = 1.0f/(1.0f + __expf(-gl));
            }
            dst[(size_t)((i2*4 + hh)*256 + j2)*32 + c] = f2bf(val);
          }
        }
      if (cb == 0 && wid < 4){
        // pair-bias: [64x128(sA)] x [128x4(w_b*log2e)]; waves 0-3 take 16-row subtiles
        bf16x8 wb[4];
        #pragma unroll
        for (int ks=0; ks<4; ++ks){
          if (lcol < 4)
            wb[ks] = *reinterpret_cast<const bf16x8*>(&Wcat[(512+lcol)*128 + ks*32 + hi*8]);
          else
            wb[ks] = (bf16x8){0,0,0,0,0,0,0,0};
        }
        {
          int st = wid;                  // 4 waves cover the 4 16-row subtiles
          f32x4 accb = {0.f,0.f,0.f,0.f};
          #pragma unroll
          for (int ks=0; ks<4; ++ks){
            int row = st*16 + lcol;
            int off = row*256 + ks*64 + lk16;
            bf16x8 a = *reinterpret_cast<const bf16x8*>(sA + (off ^ ((row&7)<<4)));
            accb = __builtin_amdgcn_mfma_f32_16x16x32_bf16(a, wb[ks], accb, 0,0,0);
          }
          if (lcol < 4){
            int mr = rb*64 + st*16 + hi*4;
            int i2 = mr >> 8, jb = mr & 255;
            *reinterpret_cast<f32x4*>(&bias4[((size_t)(lcol*64 + (jb>>2))*256 + i2)*4]) = accb;
          }
        }
      }
    } else { // cb == 2: v, transposed per (i,h)
      #pragma unroll
      for (int mi=0; mi<2; ++mi)
        #pragma unroll
        for (int ni=0; ni<2; ++ni){
          int e = wc*32 + ni*16 + lcol;
          int hh = e>>5, c = e&31;
          int mrow = rb*64 + wr*32 + mi*16 + r0;
          int i2 = mrow >> 8, j2 = mrow & 255;
          u16x4 pk;
          #pragma unroll
          for (int r=0; r<4; ++r) pk[r] = f2bf(acc[mi][ni][r]);
          *reinterpret_cast<u16x4*>(&Vt[(size_t)((i2*4 + hh)*32 + c)*256 + j2]) = pk;
        }
    }
  }
}

// ---------------- kernel 3: attention, one block per (i, h) ------------------------
// Round-13 version EXACTLY. Base-2 max-free softmax, serial halves. Liveness rule
// (3 spills measured): one half's state fills the 128-VGPR budget; do NOT extend
// live ranges across phases here.
__global__ __launch_bounds__(256, 2) void attn_kernel(
    const unsigned short* __restrict__ Qsep, const unsigned short* __restrict__ Ksep,
    const unsigned short* __restrict__ Vt, const unsigned short* __restrict__ Gsep,
    const float* __restrict__ bias4, const float* __restrict__ Z_mask,
    unsigned short* __restrict__ o_buf)
{
  __shared__ __align__(16) char sK[16384];   // [256 k-rows][64 B] swizzled
  __shared__ __align__(16) char sV[16384];   // [32 c-rows][512 B] swizzled
  __shared__ __align__(16) char sP[4096];    // per-wave 1 KiB: [16 q][64 B] XOR-swizzled
  __shared__ float smask[256];
  int ia = blockIdx.x >> 2, h = blockIdx.x & 3;
  int t = threadIdx.x;
  {
    const char* srcK = (const char*)&Ksep[(size_t)((ia*4 + h)*256)*32];
    const char* srcV = (const char*)&Vt[(size_t)((ia*4 + h)*32)*256];
    #pragma unroll
    for (int it=0; it<4; ++it){
      int off = (it*256 + t)*16;
      int rowK = off >> 6;
      *reinterpret_cast<i32x4*>(sK + (off ^ ((rowK&7)<<4))) =
        *reinterpret_cast<const i32x4*>(srcK + off);
      int rowV = off >> 9;
      *reinterpret_cast<i32x4*>(sV + (off ^ ((rowV&7)<<4))) =
        *reinterpret_cast<const i32x4*>(srcV + off);
    }
  }
  smask[t] = (1e9f * LOG2E) * (Z_mask[(size_t)t*256 + ia] - 1.0f);
  __syncthreads();

  int wid = t>>6, lane = t&63;
  int lq = lane & 15;
  int hi = lane >> 4;
  char* sPw = sP + wid*1024;
  int pswz = (lq&7)<<4;   // sP XOR swizzle (bijective within the 1 KiB chunk)
  const f32x4* b4 = reinterpret_cast<const f32x4*>(bias4);

  #pragma unroll 1
  for (int mi=0; mi<4; ++mi){
    int q0 = wid*64 + mi*16;
    int q  = q0 + lq;
    bf16x8 aq = *reinterpret_cast<const bf16x8*>(
        &Qsep[(size_t)((ia*4 + h)*256 + q)*32 + hi*8]);
    f32x4 oacc[2] = {};
    f32x4 sum4 = {0.f,0.f,0.f,0.f};
    #pragma unroll 1
    for (int half=0; half<2; ++half){
      f32x4 s[8];
      // C-init = bias4[h][g][q] + mask[k0..k0+3]  (both pre-scaled by log2e)
      #pragma unroll
      for (int ni=0; ni<8; ++ni){
        int g  = half*32 + ni*4 + hi;
        int k0 = half*128 + ni*16 + hi*4;
        f32x4 bb  = b4[(size_t)(h*64 + g)*256 + q];
        f32x4 msk = *reinterpret_cast<const f32x4*>(&smask[k0]);
        s[ni] = bb + msk;
      }
      // swapped QK^T: A=K-frag, B=Q-frag -> S^T (row=k, col=q)
      __builtin_amdgcn_s_setprio(1);
      #pragma unroll
      for (int ni=0; ni<8; ++ni){
        int krow = half*128 + ni*16 + lq;
        int off  = krow*64 + hi*16;
        bf16x8 bk = *reinterpret_cast<const bf16x8*>(sK + (off ^ ((krow&7)<<4)));
        s[ni] = __builtin_amdgcn_mfma_f32_16x16x32_bf16(bk, aq, s[ni], 0,0,0);
      }
      __builtin_amdgcn_s_setprio(0);
      // P = exp2(s) directly; accumulate denominator
      #pragma unroll
      for (int ni=0; ni<8; ++ni){
        f32x4 p;
        #pragma unroll
        for (int r=0; r<4; ++r) p[r] = __builtin_amdgcn_exp2f(s[ni][r]);
        s[ni] = p;
        sum4 += p;
      }
      // pack P -> bf16 through wave-private sP (XOR-swizzled), PV in 32-k chunks
      __builtin_amdgcn_s_setprio(1);
      #pragma unroll
      for (int ck=0; ck<4; ++ck){
        #pragma unroll
        for (int nl=0; nl<2; ++nl){
          int ni = ck*2 + nl;
          u32x2 w;
          w.x = packbf2(s[ni][0], s[ni][1]);
          w.y = packbf2(s[ni][2], s[ni][3]);
          *reinterpret_cast<u32x2*>(sPw + ((lq*64 + nl*32 + hi*8) ^ pswz)) = w;
        }
        bf16x8 ap = *reinterpret_cast<const bf16x8*>(sPw + ((lq*64 + hi*16) ^ pswz));
        int ks = half*4 + ck;
        #pragma unroll
        for (int nc=0; nc<2; ++nc){
          int vrow = nc*16 + lq;
          int voff = vrow*512 + ks*64 + hi*16;
          bf16x8 bv = *reinterpret_cast<const bf16x8*>(sV + (voff ^ ((vrow&7)<<4)));
          oacc[nc] = __builtin_amdgcn_mfma_f32_16x16x32_bf16(ap, bv, oacc[nc], 0,0,0);
        }
      }
      __builtin_amdgcn_s_setprio(0);
    }
    float sum = (sum4[0]+sum4[1]) + (sum4[2]+sum4[3]);
    sum += __shfl_xor(sum, 16, 64);
    sum += __shfl_xor(sum, 32, 64);
    float rinv[4];
    #pragma unroll
    for (int r=0; r<4; ++r)
      rinv[r] = __builtin_amdgcn_rcpf(__shfl(sum, hi*4 + r, 64));
    #pragma unroll
    for (int nc=0; nc<2; ++nc)
      #pragma unroll
      for (int r=0; r<4; ++r){
        int qo = q0 + hi*4 + r;
        float gv = bf2f(Gsep[(size_t)((ia*4 + h)*256 + qo)*32 + nc*16 + lq]);
        o_buf[(size_t)(ia*256 + qo)*128 + h*32 + nc*16 + lq] =
            f2bf(oacc[nc][r] * rinv[r] * gv);
      }
  }
}

// ---------------- kernel 4: (g*o) @ w_o^T + out_bias + Z_raw (transposed out) ------
__global__ __launch_bounds__(256) void final_kernel(
    const unsigned short* __restrict__ o_buf, const unsigned short* __restrict__ Wo_bf,
    const float* __restrict__ out_bias, const float* __restrict__ Z_raw,
    float* __restrict__ out)
{
  __shared__ __align__(16) char sA[32768];
  __shared__ __align__(16) char sB[32768];
  int rb = blockIdx.x, t = threadIdx.x;
  const char* gO = (const char*)o_buf + (size_t)rb*32768;
  #pragma unroll
  for (int it=0; it<8; ++it){
    int off = it*4096 + t*16;
    int row = off >> 8;
    int swz = off ^ ((row&7)<<4);
    *reinterpret_cast<i32x4*>(sA + swz) = *reinterpret_cast<const i32x4*>(gO + off);
    *reinterpret_cast<i32x4*>(sB + swz) = *reinterpret_cast<const i32x4*>((const char*)Wo_bf + off);
  }
  __syncthreads();
  int wid = t>>6, lane = t&63;
  int wr = wid>>1, wc = wid&1;
  int lcol = lane & 15, lk16 = (lane>>4)*16;
  f32x4 acc[4][4] = {};
  #pragma unroll
  for (int ks=0; ks<4; ++ks){
    bf16x8 a[4], b[4];
    #pragma unroll
    for (int mi=0; mi<4; ++mi){
      int row = wr*64 + mi*16 + lcol;
      int off = row*256 + ks*64 + lk16;
      a[mi] = *reinterpret_cast<const bf16x8*>(sA + (off ^ ((row&7)<<4)));
    }
    #pragma unroll
    for (int ni=0; ni<4; ++ni){
      int row = wc*64 + ni*16 + lcol;
      int off = row*256 + ks*64 + lk16;
      b[ni] = *reinterpret_cast<const bf16x8*>(sB + (off ^ ((row&7)<<4)));
    }
    #pragma unroll
    for (int mi=0; mi<4; ++mi)
      #pragma unroll
      for (int ni=0; ni<4; ++ni)
        acc[mi][ni] = __builtin_amdgcn_mfma_f32_16x16x32_bf16(a[mi], b[ni], acc[mi][ni], 0,0,0);
  }
  int r0 = (lane>>4)*4;
  #pragma unroll
  for (int mi=0; mi<4; ++mi)
    #pragma unroll
    for (int ni=0; ni<4; ++ni){
      int col = wc*64 + ni*16 + lcol;
      #pragma unroll
      for (int r=0; r<4; ++r){
        int mrow = rb*128 + wr*64 + mi*16 + r0 + r;
        int i = mrow >> 8, j = mrow & 255;
        size_t oidx = ((size_t)(j*256 + i))*128 + col;
        out[oidx] = acc[mi][ni][r] + out_bias[col] + Z_raw[oidx];
      }
    }
}

extern "C" void kernel_launch(void* const* d_in, const int* in_sizes, int n_in,
                              void* d_out, int out_size, void* d_ws, size_t ws_size,
                              hipStream_t stream)
{
  (void)in_sizes; (void)n_in; (void)out_size; (void)ws_size;
  const float* Z_raw    = (const float*)d_in[0];
  const float* Z_mask   = (const float*)d_in[1];
  const float* ln_gamma = (const float*)d_in[2];
  const float* ln_beta  = (const float*)d_in[3];
  const float* w_b      = (const float*)d_in[4];
  const float* w_qkv    = (const float*)d_in[5];
  const float* w_g      = (const float*)d_in[6];
  const float* b_g      = (const float*)d_in[7];
  const float* w_o      = (const float*)d_in[8];
  const float* out_bias = (const float*)d_in[9];
  float* out = (float*)d_out;

  char* ws = (char*)d_ws;
  unsigned short* o_buf = (unsigned short*)(ws + OBUF_OFF);
  unsigned short* Qsep  = (unsigned short*)(ws + QSEP_OFF);
  unsigned short* Ksep  = (unsigned short*)(ws + KSEP_OFF);
  unsigned short* Gsep  = (unsigned short*)(ws + GSEP_OFF);
  unsigned short* Vt    = (unsigned short*)(ws + VT_OFF);
  float*          biasb = (float*)(ws + BIAS_OFF);
  unsigned short* Wcat  = (unsigned short*)(ws + WCAT_OFF);
  unsigned short* Wo_bf = (unsigned short*)(ws + WO_OFF);

  prep_w_kernel<<<dim3(322), dim3(256), 0, stream>>>(w_qkv, w_g, w_b, w_o, Wcat, Wo_bf);
  gemm_qkvg_kernel<<<dim3(1024), dim3(512), 0, stream>>>(
      Z_raw, ln_gamma, ln_beta, Wcat, b_g, Qsep, Ksep, Gsep, Vt, biasb);
  attn_kernel<<<dim3(1024), dim3(256), 0, stream>>>(
      Qsep, Ksep, Vt, Gsep, biasb, Z_mask, o_buf);
  final_kernel<<<dim3(512), dim3(256), 0, stream>>>(o_buf, Wo_bf, out_bias, Z_raw, out);
}

// Round 23
// 79.465 us; speedup vs baseline: 1.1548x; 1.1548x over previous
//
#include <hip/hip_runtime.h>

typedef __attribute__((ext_vector_type(4))) float  f32x4;
typedef __attribute__((ext_vector_type(8))) short  bf16x8;
typedef __attribute__((ext_vector_type(4))) int    i32x4;
typedef __attribute__((ext_vector_type(2))) unsigned short u16x2;
typedef __attribute__((ext_vector_type(4))) unsigned short u16x4;
typedef __attribute__((ext_vector_type(2))) unsigned int   u32x2;

// ws layout (bytes)
#define OBUF_OFF  0u            // 65536*128 bf16 = 16 MiB
#define QSEP_OFF  16777216u     // [256 i][4 h][256 j][32 c] bf16 = 16 MiB (q, scale*log2e folded)
#define KSEP_OFF  33554432u     // [256 i][4 h][256 j][32 c] bf16 = 16 MiB
#define GSEP_OFF  50331648u     // [256 i][4 h][256 j][32 c] bf16 = 16 MiB (sigmoid(g), pre-gated)
#define VT_OFF    67108864u     // [256 i][4 h][32 c][256 j] bf16 = 16 MiB
#define BIAS_OFF  83886080u     // [4 h][64 k4][256 q][4] f32 = 1 MiB (pre-scaled by log2e)
#define WCAT_OFF  84934656u     // [516][128] bf16 (q*scale*log2e, k, v, g, w_b*log2e rows 512-515)
#define WO_OFF    85066752u     // [128][128] bf16

#define LOG2E 1.4426950408889634f

__device__ __forceinline__ unsigned short f2bf(float x){
  unsigned int u = __builtin_bit_cast(unsigned int, x);
  unsigned int r = (u + 0x7FFFu + ((u>>16)&1u)) >> 16;
  return (unsigned short)r;
}
__device__ __forceinline__ float bf2f(unsigned short b){
  unsigned int u = ((unsigned int)b) << 16;
  return __builtin_bit_cast(float, u);
}
__device__ __forceinline__ unsigned packbf2(float lo, float hi){
  return __builtin_amdgcn_perm(__builtin_bit_cast(unsigned, hi),
                               __builtin_bit_cast(unsigned, lo), 0x07060302u);
}

// ---------------- kernel 1: weight prep only (tiny: 322 blocks) --------------------
__global__ __launch_bounds__(256) void prep_w_kernel(
    const float* __restrict__ w_qkv, const float* __restrict__ w_g,
    const float* __restrict__ w_b,  const float* __restrict__ w_o,
    unsigned short* __restrict__ Wcat, unsigned short* __restrict__ Wo_bf)
{
  int idx = blockIdx.x*256 + threadIdx.x;
  if (idx < 516*128){
    int r = idx >> 7, d = idx & 127;
    float v;
    if (r < 384)      v = w_qkv[idx];
    else if (r < 512) v = w_g[(r-384)*128 + d];
    else              v = w_b[(r-512)*128 + d] * LOG2E;
    if (r < 128) v *= 0.17677669529663689f * LOG2E;  // C^-0.5 * log2e into q rows
    Wcat[idx] = f2bf(v);
  } else if (idx < 516*128 + 128*128){
    int k = idx - 516*128;
    Wo_bf[k] = f2bf(w_o[k]);
  }
}

// ---------------- kernel 2: LN (fused) + qkv+g GEMM + pair-bias, 8 waves/block -----
// Round-19 version EXACTLY (session best, 79.6us, twice verified). Gemm is
// per-wave instruction-stream-bound: occupancy 17/32/50% all give >=39us
// (rounds 17-22); 128-row tiles + 8 waves + register-direct B from L2-resident
// Wcat is the measured optimum on every tested axis (tile up AND down, LDS,
// ILP, store shape, occupancy).
__global__ __launch_bounds__(512) void gemm_qkvg_kernel(
    const float* __restrict__ Z_raw, const float* __restrict__ ln_gamma,
    const float* __restrict__ ln_beta, const unsigned short* __restrict__ Wcat,
    const float* __restrict__ b_g,
    unsigned short* __restrict__ Qsep, unsigned short* __restrict__ Ksep,
    unsigned short* __restrict__ Gsep, unsigned short* __restrict__ Vt,
    float* __restrict__ bias4)
{
  __shared__ __align__(16) char sA[32768];   // [128 rows][256 B] swizzled (LN output)
  int rb = blockIdx.x;
  int t = threadIdx.x;
  int wid = t>>6, lane = t&63;
  // LN of this block's 128 rows -> sA (2 rows/wave/pass, 8 waves => 8 passes)
  {
    int half = lane >> 5, l32 = lane & 31;
    int i0 = rb >> 1, j0 = (rb & 1) * 128;
    f32x4 g4  = *reinterpret_cast<const f32x4*>(&ln_gamma[l32*4]);
    f32x4 be4 = *reinterpret_cast<const f32x4*>(&ln_beta[l32*4]);
    #pragma unroll
    for (int it=0; it<8; ++it){
      int lr = it*16 + wid*2 + half;    // local row 0..127
      int j  = j0 + lr;
      f32x4 v = *reinterpret_cast<const f32x4*>(&Z_raw[((size_t)(j*256 + i0))*128 + l32*4]);
      float s  = (v[0]+v[1]) + (v[2]+v[3]);
      float sq = (v[0]*v[0]+v[1]*v[1]) + (v[2]*v[2]+v[3]*v[3]);
      #pragma unroll
      for (int mk=1; mk<32; mk<<=1){ s += __shfl_xor(s, mk, 64); sq += __shfl_xor(sq, mk, 64); }
      float mu   = s * (1.0f/128.0f);
      float var  = sq*(1.0f/128.0f) - mu*mu;
      float rstd = rsqrtf(var + 1e-5f);
      u16x4 o;
      #pragma unroll
      for (int e=0; e<4; ++e) o[e] = f2bf((v[e]-mu)*rstd*g4[e] + be4[e]);
      int off = lr*256 + l32*8;
      *reinterpret_cast<u16x4*>(sA + (off ^ ((lr&7)<<4))) = o;
    }
  }
  __syncthreads();
  int wr = wid>>2, wc = wid&3;          // 64-row half x 32-col quarter
  int lcol = lane & 15, lk16 = (lane>>4)*16;
  int r0 = (lane>>4)*4, hi = lane>>4;

  #pragma unroll
  for (int cb=0; cb<4; ++cb){
    f32x4 acc[4][2] = {};
    #pragma unroll
    for (int ks=0; ks<4; ++ks){
      bf16x8 a[4], b[2];
      #pragma unroll
      for (int mi=0; mi<4; ++mi){
        int row = wr*64 + mi*16 + lcol;
        int off = row*256 + ks*64 + lk16;
        a[mi] = *reinterpret_cast<const bf16x8*>(sA + (off ^ ((row&7)<<4)));
      }
      #pragma unroll
      for (int ni=0; ni<2; ++ni){
        int brow = cb*128 + wc*32 + ni*16 + lcol;   // weight row (L2-resident)
        b[ni] = *reinterpret_cast<const bf16x8*>(&Wcat[brow*128 + ks*32 + hi*8]);
      }
      #pragma unroll
      for (int mi=0; mi<4; ++mi)
        #pragma unroll
        for (int ni=0; ni<2; ++ni)
          acc[mi][ni] = __builtin_amdgcn_mfma_f32_16x16x32_bf16(a[mi], b[ni], acc[mi][ni], 0,0,0);
    }
    if (cb != 2){
      unsigned short* __restrict__ dst = (cb==0) ? Qsep : (cb==1 ? Ksep : Gsep);
      #pragma unroll
      for (int mi=0; mi<4; ++mi)
        #pragma unroll
        for (int ni=0; ni<2; ++ni){
          int e = wc*32 + ni*16 + lcol;      // h = e>>5, c = e&31
          int hh = e>>5, c = e&31;
          int mrow = rb*128 + wr*64 + mi*16 + r0;
          #pragma unroll
          for (int r=0; r<4; ++r){
            int m = mrow + r;
            int i2 = m >> 8, j2 = m & 255;
            float val = acc[mi][ni][r];
            if (cb == 3){
              float gl = val + b_g[e];
              val = 1.0f/(1.0f + __expf(-gl));
            }
            dst[(size_t)((i2*4 + hh)*256 + j2)*32 + c] = f2bf(val);
          }
        }
      if (cb == 0){
        // pair-bias: [128x128(sA)] x [128x4(w_b*log2e)]; one 16-row subtile/wave
        bf16x8 wb[4];
        #pragma unroll
        for (int ks=0; ks<4; ++ks){
          if (lcol < 4)
            wb[ks] = *reinterpret_cast<const bf16x8*>(&Wcat[(512+lcol)*128 + ks*32 + hi*8]);
          else
            wb[ks] = (bf16x8){0,0,0,0,0,0,0,0};
        }
        {
          int st = wid;                  // 8 waves cover the 8 16-row subtiles
          f32x4 accb = {0.f,0.f,0.f,0.f};
          #pragma unroll
          for (int ks=0; ks<4; ++ks){
            int row = st*16 + lcol;
            int off = row*256 + ks*64 + lk16;
            bf16x8 a = *reinterpret_cast<const bf16x8*>(sA + (off ^ ((row&7)<<4)));
            accb = __builtin_amdgcn_mfma_f32_16x16x32_bf16(a, wb[ks], accb, 0,0,0);
          }
          if (lcol < 4){
            int mr = rb*128 + st*16 + hi*4;
            int i2 = mr >> 8, jb = mr & 255;
            *reinterpret_cast<f32x4*>(&bias4[((size_t)(lcol*64 + (jb>>2))*256 + i2)*4]) = accb;
          }
        }
      }
    } else { // cb == 2: v, transposed per (i,h)
      #pragma unroll
      for (int mi=0; mi<4; ++mi)
        #pragma unroll
        for (int ni=0; ni<2; ++ni){
          int e = wc*32 + ni*16 + lcol;
          int hh = e>>5, c = e&31;
          int mrow = rb*128 + wr*64 + mi*16 + r0;
          int i2 = mrow >> 8, j2 = mrow & 255;
          u16x4 pk;
          #pragma unroll
          for (int r=0; r<4; ++r) pk[r] = f2bf(acc[mi][ni][r]);
          *reinterpret_cast<u16x4*>(&Vt[(size_t)((i2*4 + hh)*32 + c)*256 + j2]) = pk;
        }
    }
  }
}

// ---------------- kernel 3: attention, one block per (i, h) ------------------------
// Round-13 version EXACTLY. Base-2 max-free softmax, serial halves. Liveness rule
// (3 spills measured): one half's state fills the 128-VGPR budget; do NOT extend
// live ranges across phases here.
__global__ __launch_bounds__(256, 2) void attn_kernel(
    const unsigned short* __restrict__ Qsep, const unsigned short* __restrict__ Ksep,
    const unsigned short* __restrict__ Vt, const unsigned short* __restrict__ Gsep,
    const float* __restrict__ bias4, const float* __restrict__ Z_mask,
    unsigned short* __restrict__ o_buf)
{
  __shared__ __align__(16) char sK[16384];   // [256 k-rows][64 B] swizzled
  __shared__ __align__(16) char sV[16384];   // [32 c-rows][512 B] swizzled
  __shared__ __align__(16) char sP[4096];    // per-wave 1 KiB: [16 q][64 B] XOR-swizzled
  __shared__ float smask[256];
  int ia = blockIdx.x >> 2, h = blockIdx.x & 3;
  int t = threadIdx.x;
  {
    const char* srcK = (const char*)&Ksep[(size_t)((ia*4 + h)*256)*32];
    const char* srcV = (const char*)&Vt[(size_t)((ia*4 + h)*32)*256];
    #pragma unroll
    for (int it=0; it<4; ++it){
      int off = (it*256 + t)*16;
      int rowK = off >> 6;
      *reinterpret_cast<i32x4*>(sK + (off ^ ((rowK&7)<<4))) =
        *reinterpret_cast<const i32x4*>(srcK + off);
      int rowV = off >> 9;
      *reinterpret_cast<i32x4*>(sV + (off ^ ((rowV&7)<<4))) =
        *reinterpret_cast<const i32x4*>(srcV + off);
    }
  }
  smask[t] = (1e9f * LOG2E) * (Z_mask[(size_t)t*256 + ia] - 1.0f);
  __syncthreads();

  int wid = t>>6, lane = t&63;
  int lq = lane & 15;
  int hi = lane >> 4;
  char* sPw = sP + wid*1024;
  int pswz = (lq&7)<<4;   // sP XOR swizzle (bijective within the 1 KiB chunk)
  const f32x4* b4 = reinterpret_cast<const f32x4*>(bias4);

  #pragma unroll 1
  for (int mi=0; mi<4; ++mi){
    int q0 = wid*64 + mi*16;
    int q  = q0 + lq;
    bf16x8 aq = *reinterpret_cast<const bf16x8*>(
        &Qsep[(size_t)((ia*4 + h)*256 + q)*32 + hi*8]);
    f32x4 oacc[2] = {};
    f32x4 sum4 = {0.f,0.f,0.f,0.f};
    #pragma unroll 1
    for (int half=0; half<2; ++half){
      f32x4 s[8];
      // C-init = bias4[h][g][q] + mask[k0..k0+3]  (both pre-scaled by log2e)
      #pragma unroll
      for (int ni=0; ni<8; ++ni){
        int g  = half*32 + ni*4 + hi;
        int k0 = half*128 + ni*16 + hi*4;
        f32x4 bb  = b4[(size_t)(h*64 + g)*256 + q];
        f32x4 msk = *reinterpret_cast<const f32x4*>(&smask[k0]);
        s[ni] = bb + msk;
      }
      // swapped QK^T: A=K-frag, B=Q-frag -> S^T (row=k, col=q)
      __builtin_amdgcn_s_setprio(1);
      #pragma unroll
      for (int ni=0; ni<8; ++ni){
        int krow = half*128 + ni*16 + lq;
        int off  = krow*64 + hi*16;
        bf16x8 bk = *reinterpret_cast<const bf16x8*>(sK + (off ^ ((krow&7)<<4)));
        s[ni] = __builtin_amdgcn_mfma_f32_16x16x32_bf16(bk, aq, s[ni], 0,0,0);
      }
      __builtin_amdgcn_s_setprio(0);
      // P = exp2(s) directly; accumulate denominator
      #pragma unroll
      for (int ni=0; ni<8; ++ni){
        f32x4 p;
        #pragma unroll
        for (int r=0; r<4; ++r) p[r] = __builtin_amdgcn_exp2f(s[ni][r]);
        s[ni] = p;
        sum4 += p;
      }
      // pack P -> bf16 through wave-private sP (XOR-swizzled), PV in 32-k chunks
      __builtin_amdgcn_s_setprio(1);
      #pragma unroll
      for (int ck=0; ck<4; ++ck){
        #pragma unroll
        for (int nl=0; nl<2; ++nl){
          int ni = ck*2 + nl;
          u32x2 w;
          w.x = packbf2(s[ni][0], s[ni][1]);
          w.y = packbf2(s[ni][2], s[ni][3]);
          *reinterpret_cast<u32x2*>(sPw + ((lq*64 + nl*32 + hi*8) ^ pswz)) = w;
        }
        bf16x8 ap = *reinterpret_cast<const bf16x8*>(sPw + ((lq*64 + hi*16) ^ pswz));
        int ks = half*4 + ck;
        #pragma unroll
        for (int nc=0; nc<2; ++nc){
          int vrow = nc*16 + lq;
          int voff = vrow*512 + ks*64 + hi*16;
          bf16x8 bv = *reinterpret_cast<const bf16x8*>(sV + (voff ^ ((vrow&7)<<4)));
          oacc[nc] = __builtin_amdgcn_mfma_f32_16x16x32_bf16(ap, bv, oacc[nc], 0,0,0);
        }
      }
      __builtin_amdgcn_s_setprio(0);
    }
    float sum = (sum4[0]+sum4[1]) + (sum4[2]+sum4[3]);
    sum += __shfl_xor(sum, 16, 64);
    sum += __shfl_xor(sum, 32, 64);
    float rinv[4];
    #pragma unroll
    for (int r=0; r<4; ++r)
      rinv[r] = __builtin_amdgcn_rcpf(__shfl(sum, hi*4 + r, 64));
    #pragma unroll
    for (int nc=0; nc<2; ++nc)
      #pragma unroll
      for (int r=0; r<4; ++r){
        int qo = q0 + hi*4 + r;
        float gv = bf2f(Gsep[(size_t)((ia*4 + h)*256 + qo)*32 + nc*16 + lq]);
        o_buf[(size_t)(ia*256 + qo)*128 + h*32 + nc*16 + lq] =
            f2bf(oacc[nc][r] * rinv[r] * gv);
      }
  }
}

// ---------------- kernel 4: (g*o) @ w_o^T + out_bias + Z_raw (transposed out) ------
__global__ __launch_bounds__(256) void final_kernel(
    const unsigned short* __restrict__ o_buf, const unsigned short* __restrict__ Wo_bf,
    const float* __restrict__ out_bias, const float* __restrict__ Z_raw,
    float* __restrict__ out)
{
  __shared__ __align__(16) char sA[32768];
  __shared__ __align__(16) char sB[32768];
  int rb = blockIdx.x, t = threadIdx.x;
  const char* gO = (const char*)o_buf + (size_t)rb*32768;
  #pragma unroll
  for (int it=0; it<8; ++it){
    int off = it*4096 + t*16;
    int row = off >> 8;
    int swz = off ^ ((row&7)<<4);
    *reinterpret_cast<i32x4*>(sA + swz) = *reinterpret_cast<const i32x4*>(gO + off);
    *reinterpret_cast<i32x4*>(sB + swz) = *reinterpret_cast<const i32x4*>((const char*)Wo_bf + off);
  }
  __syncthreads();
  int wid = t>>6, lane = t&63;
  int wr = wid>>1, wc = wid&1;
  int lcol = lane & 15, lk16 = (lane>>4)*16;
  f32x4 acc[4][4] = {};
  #pragma unroll
  for (int ks=0; ks<4; ++ks){
    bf16x8 a[4], b[4];
    #pragma unroll
    for (int mi=0; mi<4; ++mi){
      int row = wr*64 + mi*16 + lcol;
      int off = row*256 + ks*64 + lk16;
      a[mi] = *reinterpret_cast<const bf16x8*>(sA + (off ^ ((row&7)<<4)));
    }
    #pragma unroll
    for (int ni=0; ni<4; ++ni){
      int row = wc*64 + ni*16 + lcol;
      int off = row*256 + ks*64 + lk16;
      b[ni] = *reinterpret_cast<const bf16x8*>(sB + (off ^ ((row&7)<<4)));
    }
    #pragma unroll
    for (int mi=0; mi<4; ++mi)
      #pragma unroll
      for (int ni=0; ni<4; ++ni)
        acc[mi][ni] = __builtin_amdgcn_mfma_f32_16x16x32_bf16(a[mi], b[ni], acc[mi][ni], 0,0,0);
  }
  int r0 = (lane>>4)*4;
  #pragma unroll
  for (int mi=0; mi<4; ++mi)
    #pragma unroll
    for (int ni=0; ni<4; ++ni){
      int col = wc*64 + ni*16 + lcol;
      #pragma unroll
      for (int r=0; r<4; ++r){
        int mrow = rb*128 + wr*64 + mi*16 + r0 + r;
        int i = mrow >> 8, j = mrow & 255;
        size_t oidx = ((size_t)(j*256 + i))*128 + col;
        out[oidx] = acc[mi][ni][r] + out_bias[col] + Z_raw[oidx];
      }
    }
}

extern "C" void kernel_launch(void* const* d_in, const int* in_sizes, int n_in,
                              void* d_out, int out_size, void* d_ws, size_t ws_size,
                              hipStream_t stream)
{
  (void)in_sizes; (void)n_in; (void)out_size; (void)ws_size;
  const float* Z_raw    = (const float*)d_in[0];
  const float* Z_mask   = (const float*)d_in[1];
  const float* ln_gamma = (const float*)d_in[2];
  const float* ln_beta  = (const float*)d_in[3];
  const float* w_b      = (const float*)d_in[4];
  const float* w_qkv    = (const float*)d_in[5];
  const float* w_g      = (const float*)d_in[6];
  const float* b_g      = (const float*)d_in[7];
  const float* w_o      = (const float*)d_in[8];
  const float* out_bias = (const float*)d_in[9];
  float* out = (float*)d_out;

  char* ws = (char*)d_ws;
  unsigned short* o_buf = (unsigned short*)(ws + OBUF_OFF);
  unsigned short* Qsep  = (unsigned short*)(ws + QSEP_OFF);
  unsigned short* Ksep  = (unsigned short*)(ws + KSEP_OFF);
  unsigned short* Gsep  = (unsigned short*)(ws + GSEP_OFF);
  unsigned short* Vt    = (unsigned short*)(ws + VT_OFF);
  float*          biasb = (float*)(ws + BIAS_OFF);
  unsigned short* Wcat  = (unsigned short*)(ws + WCAT_OFF);
  unsigned short* Wo_bf = (unsigned short*)(ws + WO_OFF);

  prep_w_kernel<<<dim3(322), dim3(256), 0, stream>>>(w_qkv, w_g, w_b, w_o, Wcat, Wo_bf);
  gemm_qkvg_kernel<<<dim3(512), dim3(512), 0, stream>>>(
      Z_raw, ln_gamma, ln_beta, Wcat, b_g, Qsep, Ksep, Gsep, Vt, biasb);
  attn_kernel<<<dim3(1024), dim3(256), 0, stream>>>(
      Qsep, Ksep, Vt, Gsep, biasb, Z_mask, o_buf);
  final_kernel<<<dim3(512), dim3(256), 0, stream>>>(o_buf, Wo_bf, out_bias, Z_raw, out);
}